// Round 17
// baseline (267.894 us; speedup 1.0000x reference)
//
#include <hip/hip_runtime.h>
#include <hip/hip_fp16.h>
#include <math.h>

#define NN 100000
#define NE 1600000
#define D  64
#define NBLK 391  // ceil(NN/256)
#define AGG_COUNTER 400

typedef _Float16 half2v __attribute__((ext_vector_type(2)));
typedef int int2v __attribute__((ext_vector_type(2)));
typedef unsigned int uint2v __attribute__((ext_vector_type(2)));

// in-register packed entry: [col:17][ex_fp16_no_sign:15]  (col < 2^17, ex in (0,1])
__device__ __forceinline__ unsigned int pack_entry(int col, float ex) {
    unsigned short hb = __half_as_ushort(__float2half(ex));
    return ((unsigned int)col << 15) | (unsigned int)(hb & 0x7FFFu);
}
__device__ __forceinline__ float unpack_ex(unsigned int pk) {
    return __half2float(__ushort_as_half((unsigned short)(pk & 0x7FFFu)));
}

__device__ __forceinline__ float dot2acc(int a, unsigned int b, float c) {
#if defined(__has_builtin) && __has_builtin(__builtin_amdgcn_fdot2)
    return __builtin_amdgcn_fdot2(__builtin_bit_cast(half2v, a),
                                  __builtin_bit_cast(half2v, b), c, false);
#else
    float2 fa = __half22float2(*(const __half2*)&a);
    float2 fb = __half22float2(*(const __half2*)&b);
    return fmaf(fa.y, fb.y, fmaf(fa.x, fb.x, c));
#endif
}

// ---------------- K_prep_count: count atomics issued EARLY, consumed LATE (latency hidden
//                  under prep); zx[n][0:64]=z/||z||, zx[n][64:128]=x@W^T (fp16) ----------------
__global__ __launch_bounds__(256) void k_prep_count(const float* __restrict__ z,
                                                    const float* __restrict__ x,
                                                    const float* __restrict__ W,
                                                    __half* __restrict__ zx,
                                                    const int* __restrict__ ei,
                                                    int* __restrict__ cnt8,
                                                    unsigned int* __restrict__ rankr) {
    // ---- count phase part 1: issue the ei load immediately ----
    const int myc = (blockIdx.x & 7) * NN;
    const unsigned int xcdbits = (unsigned int)(blockIdx.x & 7) << 12;
    int e0 = (blockIdx.x * 256 + threadIdx.x) * 2;  // blocks 0..3124 cover NE exactly
    bool havec = e0 < NE;
    int2v rr;
    if (havec) rr = __builtin_nontemporal_load((const int2v*)(ei + e0));

    __shared__ unsigned int WtP[32 * 64];  // WtP[d2*64 + j] = half2(W[j][2*d2], W[j][2*d2+1]), 8 KB
    {
        const float2* W2 = (const float2*)W;
        for (int i = threadIdx.x; i < 2048; i += 256) {
            int j = i >> 5, d2 = i & 31;
            float2 wp = W2[j * 32 + d2];  // coalesced pair read of row j
            half2v h;
            h.x = (_Float16)wp.x;
            h.y = (_Float16)wp.y;
            WtP[d2 * 64 + j] = __builtin_bit_cast(unsigned int, h);
        }
    }
    __syncthreads();

    // ---- count phase part 2: issue atomics; results consumed after the prep loop ----
    int rk0 = 0, rk1 = 0;
    if (havec) {
        rk0 = atomicAdd(&cnt8[myc + rr.x], 1);
        rk1 = atomicAdd(&cnt8[myc + rr.y], 1);
    }

    // ---- prep phase ----
    const int lane = threadIdx.x & 63;
    int wave = blockIdx.x * 4 + (threadIdx.x >> 6);
    int nWaves = gridDim.x * 4;
    for (int n = wave; n < NN; n += nWaves) {
        float zv = z[n * D + lane];
        float s = zv * zv;
#pragma unroll
        for (int off = 32; off; off >>= 1) s += __shfl_xor(s, off);
        float inv = 1.0f / sqrtf(fmaxf(s, 1e-18f));
        zx[(size_t)n * 128 + lane] = __float2half(zv * inv);
        // pack x row into lane-held half2 pairs: lane i holds (x[2*(i&31)], x[2*(i&31)+1])
        float xv = x[n * D + lane];
        float pa = __shfl(xv, 2 * (lane & 31));
        float pb = __shfl(xv, 2 * (lane & 31) + 1);
        half2v pkh;
        pkh.x = (_Float16)pa;
        pkh.y = (_Float16)pb;
        int pki = __builtin_bit_cast(int, pkh);
        float y = 0.0f;
#pragma unroll
        for (int d2 = 0; d2 < 32; ++d2) {
            int pv = __shfl(pki, d2);               // (x[2*d2], x[2*d2+1]) broadcast
            unsigned int wv = WtP[d2 * 64 + lane];  // 2-way alias, free
            y = dot2acc(pv, wv, y);
        }
        zx[(size_t)n * 128 + 64 + lane] = __float2half(y);
    }

    // ---- count phase part 3: pack + store (atomic latency hidden above) ----
    if (havec) {
        uint2v pk;
        pk.x = ((unsigned int)rr.x << 15) | xcdbits | (unsigned int)rk0;  // [r:17][xcd:3][rank:12]
        pk.y = ((unsigned int)rr.y << 15) | xcdbits | (unsigned int)rk1;
        __builtin_nontemporal_store(pk, (uint2v*)(rankr + e0));
    }
}

// ---------------- K_scan: single-kernel exclusive scan (aggregate publish + spin) ----------------
// agg[0..390]: block aggregates; agg[AGG_COUNTER]: done counter. Zeroed by host memset.
// All 391 blocks (1564 waves, 1 KB LDS) are trivially co-resident -> spin is safe.
__global__ __launch_bounds__(256) void k_scan(const int* __restrict__ cnt8,
                                              int* __restrict__ agg,
                                              int* __restrict__ row_start,
                                              int* __restrict__ row_start8,
                                              int* __restrict__ tot) {
    __shared__ int sh[256];
    const int tid = threadIdx.x;
    const int bid = blockIdx.x;
    int gid = bid * 256 + tid;
    int c[8];
    int s8 = 0;
    if (gid < NN) {
#pragma unroll
        for (int k = 0; k < 8; ++k) {
            c[k] = cnt8[k * NN + gid];
            s8 += c[k];
        }
    }
    // block-local inclusive scan (Kogge-Stone)
    sh[tid] = s8;
    __syncthreads();
    for (int off = 1; off < 256; off <<= 1) {
        int t = (tid >= off) ? sh[tid - off] : 0;
        __syncthreads();
        sh[tid] += t;
        __syncthreads();
    }
    int incl = sh[tid];
    // publish aggregate (device scope, release), bump done counter
    if (tid == 255) {
        __hip_atomic_store(&agg[bid], incl, __ATOMIC_RELEASE, __HIP_MEMORY_SCOPE_AGENT);
        __hip_atomic_fetch_add(&agg[AGG_COUNTER], 1, __ATOMIC_RELEASE, __HIP_MEMORY_SCOPE_AGENT);
    }
    // wait for all aggregates
    if (tid == 0) {
        while (__hip_atomic_load(&agg[AGG_COUNTER], __ATOMIC_ACQUIRE, __HIP_MEMORY_SCOPE_AGENT) < NBLK) {
        }
    }
    __syncthreads();
    // sum predecessors' aggregates (each thread <=2 agent-scope loads, then LDS reduce)
    int mysum = 0;
    for (int j = tid; j < bid; j += 256)
        mysum += __hip_atomic_load(&agg[j], __ATOMIC_RELAXED, __HIP_MEMORY_SCOPE_AGENT);
    sh[tid] = mysum;
    __syncthreads();
    for (int off = 128; off; off >>= 1) {
        if (tid < off) sh[tid] += sh[tid + off];
        __syncthreads();
    }
    int bbase = sh[0];
    if (gid >= NN) return;
    int ex = bbase + incl - s8;  // global exclusive prefix
    row_start[gid] = ex;
    tot[gid] = s8;
    int base = ex;
#pragma unroll
    for (int k = 0; k < 8; ++k) {
        row_start8[k * NN + gid] = base;
        base += c[k];
    }
}

// ---------------- K_place: atomic-free colidx scatter, 2 edges per thread ----------------
__global__ __launch_bounds__(256) void k_place(const int* __restrict__ ei,
                                               const unsigned int* __restrict__ rankr,
                                               const int* __restrict__ row_start8,
                                               int* __restrict__ colidx) {
    int e0 = (blockIdx.x * 256 + threadIdx.x) * 2;
    if (e0 >= NE) return;
    uint2v rr = __builtin_nontemporal_load((const uint2v*)(rankr + e0));
    int2v cc = __builtin_nontemporal_load((const int2v*)(ei + NE + e0));
    int r0 = (int)(rr.x >> 15), x0 = (int)((rr.x >> 12) & 7u), k0 = (int)(rr.x & 0xFFFu);
    int r1 = (int)(rr.y >> 15), x1 = (int)((rr.y >> 12) & 7u), k1 = (int)(rr.y & 0xFFFu);
    __builtin_nontemporal_store(cc.x, &colidx[row_start8[x0 * NN + r0] + k0]);
    __builtin_nontemporal_store(cc.y, &colidx[row_start8[x1 * NN + r1] + k1]);
}

// ---------------- K_node: 4 nodes per wave (16 lanes each); fused dot+exp+softmax+gather ----------------
__global__ __launch_bounds__(256) void k_node(const __half* __restrict__ zx,
                                              const int* __restrict__ colidx,
                                              const int* __restrict__ row_start,
                                              const int* __restrict__ tot,
                                              const float* __restrict__ b,
                                              const float* __restrict__ alpha_p,
                                              const float* __restrict__ bias_p,
                                              float* __restrict__ out) {
    const int lane = threadIdx.x & 63;
    const int sub = lane & 15;  // edge slot within my node's group
    int w = (blockIdx.x * blockDim.x + threadIdx.x) >> 6;
    int nb = w * 4;  // 4 nodes per wave; grid sized exactly
    int n = nb + (lane >> 4);
    const float alpha = *alpha_p;
    const float bias = *bias_p;
    const float Mest = fabsf(alpha) + bias;  // >= max logit since |corr| <= 1
    int rs = row_start[n];
    int c = tot[n];
    float bv = b[lane];
    const float4* zi4 = (const float4*)(zx + (size_t)n * 128);
    float4 zi[8];
#pragma unroll
    for (int k = 0; k < 8; ++k) zi[k] = zi4[k];
    int cmax = c;
    cmax = max(cmax, __shfl_xor(cmax, 16));
    cmax = max(cmax, __shfl_xor(cmax, 32));
    float a0A = 0.0f, a0B = 0.0f, a1A = 0.0f, a1B = 0.0f;
    float a2A = 0.0f, a2B = 0.0f, a3A = 0.0f, a3B = 0.0f;
    float dsum = 0.0f;
    for (int base = 0; base < cmax; base += 16) {
        int idx = base + sub;
        bool valid = idx < c;
        int col = valid ? colidx[rs + idx] : 0;
        // ---- phase A: in-lane dot(zn[n], zn[col]), 4 independent fdot2 chains ----
        const float4* zj4 = (const float4*)(zx + (size_t)col * 128);
        float4 zj[8];
#pragma unroll
        for (int k = 0; k < 8; ++k) zj[k] = zj4[k];
        float d0 = 0.0f, d1 = 0.0f, d2 = 0.0f, d3 = 0.0f;
#pragma unroll
        for (int k = 0; k < 8; ++k) {
            const int* ha = (const int*)&zi[k];
            const unsigned int* hb = (const unsigned int*)&zj[k];
            d0 = dot2acc(ha[0], hb[0], d0);
            d1 = dot2acc(ha[1], hb[1], d1);
            d2 = dot2acc(ha[2], hb[2], d2);
            d3 = dot2acc(ha[3], hb[3], d3);
        }
        float dot = (d0 + d1) + (d2 + d3);
        float ex = valid ? __expf(alpha * dot + bias - Mest) : 0.0f;
        unsigned int pk = pack_entry(col, ex);
        // group-local denom butterfly (4 steps over 16 lanes)
        float t = ex;
        t += __shfl_xor(t, 1);
        t += __shfl_xor(t, 2);
        t += __shfl_xor(t, 4);
        t += __shfl_xor(t, 8);
        dsum += t;
        // ---- phase B: per group, broadcast + coalesced xw gather ----
#define PHASE_B(GG, ACCA, ACCB)                                                                    \
        {                                                                                          \
            int cg = __shfl(c, GG * 16);                                                           \
            int mg = cg - base;                                                                    \
            mg = mg > 16 ? 16 : mg;                                                               \
            int j = 0;                                                                             \
            for (; j + 4 <= mg; j += 4) {                                                          \
                unsigned int q0 = (unsigned int)__builtin_amdgcn_readlane((int)pk, GG * 16 + j);   \
                unsigned int q1 = (unsigned int)__builtin_amdgcn_readlane((int)pk, GG * 16 + j + 1); \
                unsigned int q2 = (unsigned int)__builtin_amdgcn_readlane((int)pk, GG * 16 + j + 2); \
                unsigned int q3 = (unsigned int)__builtin_amdgcn_readlane((int)pk, GG * 16 + j + 3); \
                float x0 = __half2float(zx[(size_t)(q0 >> 15) * 128 + 64 + lane]);                 \
                float x1 = __half2float(zx[(size_t)(q1 >> 15) * 128 + 64 + lane]);                 \
                float x2 = __half2float(zx[(size_t)(q2 >> 15) * 128 + 64 + lane]);                 \
                float x3 = __half2float(zx[(size_t)(q3 >> 15) * 128 + 64 + lane]);                 \
                ACCA = fmaf(unpack_ex(q0), x0, ACCA);                                              \
                ACCB = fmaf(unpack_ex(q1), x1, ACCB);                                              \
                ACCA = fmaf(unpack_ex(q2), x2, ACCA);                                              \
                ACCB = fmaf(unpack_ex(q3), x3, ACCB);                                              \
            }                                                                                      \
            for (; j < mg; ++j) {                                                                  \
                unsigned int q0 = (unsigned int)__builtin_amdgcn_readlane((int)pk, GG * 16 + j);   \
                float x0 = __half2float(zx[(size_t)(q0 >> 15) * 128 + 64 + lane]);                 \
                ACCA = fmaf(unpack_ex(q0), x0, ACCA);                                              \
            }                                                                                      \
        }
        PHASE_B(0, a0A, a0B)
        PHASE_B(1, a1A, a1B)
        PHASE_B(2, a2A, a2B)
        PHASE_B(3, a3A, a3B)
#undef PHASE_B
    }
    float dg0 = __shfl(dsum, 0);
    float dg1 = __shfl(dsum, 16);
    float dg2 = __shfl(dsum, 32);
    float dg3 = __shfl(dsum, 48);
    out[(size_t)(nb + 0) * D + lane] = (a0A + a0B) / (dg0 + 1e-9f) + bv;
    out[(size_t)(nb + 1) * D + lane] = (a1A + a1B) / (dg1 + 1e-9f) + bv;
    out[(size_t)(nb + 2) * D + lane] = (a2A + a2B) / (dg2 + 1e-9f) + bv;
    out[(size_t)(nb + 3) * D + lane] = (a3A + a3B) / (dg3 + 1e-9f) + bv;
}

extern "C" void kernel_launch(void* const* d_in, const int* in_sizes, int n_in,
                              void* d_out, int out_size, void* d_ws, size_t ws_size,
                              hipStream_t stream) {
    const float* x = (const float*)d_in[0];
    const int* ei = (const int*)d_in[1];  // [2, NE] int32
    const float* z = (const float*)d_in[2];
    const float* W = (const float*)d_in[3];
    const float* b = (const float*)d_in[4];
    const float* alpha = (const float*)d_in[5];
    const float* bias_edge = (const float*)d_in[6];
    float* out = (float*)d_out;  // [NN, D]

    // workspace layout (~46 MB)
    char* ws = (char*)d_ws;
    size_t off = 0;
    __half* zx = (__half*)(ws + off); off += (size_t)NN * 128 * 2;           // 25.6 MB
    int* colidx = (int*)(ws + off); off += (size_t)NE * 4;                   // 6.4 MB
    unsigned int* rankr = (unsigned int*)(ws + off); off += (size_t)NE * 4;  // 6.4 MB
    int* cnt8 = (int*)(ws + off); off += (size_t)8 * NN * 4;                 // 3.2 MB
    int* agg = (int*)(ws + off); off += 512 * 4;                             // aggregates + counter
    int* row_start8 = (int*)(ws + off); off += (size_t)8 * NN * 4;           // 3.2 MB
    int* row_start = (int*)(ws + off); off += (size_t)NN * 4;
    int* tot = (int*)(ws + off); off += (size_t)NN * 4;

    // zero cnt8 AND agg in one memset (they are adjacent)
    hipMemsetAsync(cnt8, 0, (size_t)8 * NN * 4 + 512 * 4, stream);
    k_prep_count<<<4096, 256, 0, stream>>>(z, x, W, zx, ei, cnt8, rankr);
    k_scan<<<NBLK, 256, 0, stream>>>(cnt8, agg, row_start, row_start8, tot);
    k_place<<<(NE / 2 + 255) / 256, 256, 0, stream>>>(ei, rankr, row_start8, colidx);
    // 4 nodes per wave, 16 nodes per 256-thread block -> exactly NN/16 = 6250 blocks
    k_node<<<NN / 16, 256, 0, stream>>>(zx, colidx, row_start, tot, b, alpha, bias_edge, out);
}

// Round 18
// 255.107 us; speedup vs baseline: 1.0501x; 1.0501x over previous
//
#include <hip/hip_runtime.h>
#include <hip/hip_fp16.h>
#include <math.h>

#define NN 100000
#define NE 1600000
#define D  64
#define NBLK 391  // ceil(NN/256)
#define AGG_COUNTER 400

typedef _Float16 half2v __attribute__((ext_vector_type(2)));
typedef int int2v __attribute__((ext_vector_type(2)));
typedef unsigned int uint2v __attribute__((ext_vector_type(2)));

// in-register packed entry: [col:17][ex_fp16_no_sign:15]  (col < 2^17, ex in (0,1])
__device__ __forceinline__ unsigned int pack_entry(int col, float ex) {
    unsigned short hb = __half_as_ushort(__float2half(ex));
    return ((unsigned int)col << 15) | (unsigned int)(hb & 0x7FFFu);
}
__device__ __forceinline__ float unpack_ex(unsigned int pk) {
    return __half2float(__ushort_as_half((unsigned short)(pk & 0x7FFFu)));
}

__device__ __forceinline__ float dot2acc(int a, unsigned int b, float c) {
#if defined(__has_builtin) && __has_builtin(__builtin_amdgcn_fdot2)
    return __builtin_amdgcn_fdot2(__builtin_bit_cast(half2v, a),
                                  __builtin_bit_cast(half2v, b), c, false);
#else
    float2 fa = __half22float2(*(const __half2*)&a);
    float2 fb = __half22float2(*(const __half2*)&b);
    return fmaf(fa.y, fb.y, fmaf(fa.x, fb.x, c));
#endif
}

// ---------------- K_prep_count (round-13 ordering): zx[n][0:64]=z/||z||,
//                  zx[n][64:128]=x@W^T (fp16); then count into cnt8[bid&7][r] ----------------
__global__ __launch_bounds__(256) void k_prep_count(const float* __restrict__ z,
                                                    const float* __restrict__ x,
                                                    const float* __restrict__ W,
                                                    __half* __restrict__ zx,
                                                    const int* __restrict__ ei,
                                                    int* __restrict__ cnt8,
                                                    unsigned int* __restrict__ rankr) {
    __shared__ unsigned int WtP[32 * 64];  // WtP[d2*64 + j] = half2(W[j][2*d2], W[j][2*d2+1]), 8 KB
    {
        const float2* W2 = (const float2*)W;
        for (int i = threadIdx.x; i < 2048; i += 256) {
            int j = i >> 5, d2 = i & 31;
            float2 wp = W2[j * 32 + d2];  // coalesced pair read of row j
            half2v h;
            h.x = (_Float16)wp.x;
            h.y = (_Float16)wp.y;
            WtP[d2 * 64 + j] = __builtin_bit_cast(unsigned int, h);
        }
    }
    __syncthreads();
    const int lane = threadIdx.x & 63;
    int wave = blockIdx.x * 4 + (threadIdx.x >> 6);
    int nWaves = gridDim.x * 4;
    for (int n = wave; n < NN; n += nWaves) {
        float zv = z[n * D + lane];
        float s = zv * zv;
#pragma unroll
        for (int off = 32; off; off >>= 1) s += __shfl_xor(s, off);
        float inv = 1.0f / sqrtf(fmaxf(s, 1e-18f));
        zx[(size_t)n * 128 + lane] = __float2half(zv * inv);
        // pack x row into lane-held half2 pairs: lane i holds (x[2*(i&31)], x[2*(i&31)+1])
        float xv = x[n * D + lane];
        float pa = __shfl(xv, 2 * (lane & 31));
        float pb = __shfl(xv, 2 * (lane & 31) + 1);
        half2v pkh;
        pkh.x = (_Float16)pa;
        pkh.y = (_Float16)pb;
        int pki = __builtin_bit_cast(int, pkh);
        float y = 0.0f;
#pragma unroll
        for (int d2 = 0; d2 < 32; ++d2) {
            int pv = __shfl(pki, d2);               // (x[2*d2], x[2*d2+1]) broadcast
            unsigned int wv = WtP[d2 * 64 + lane];  // 2-way alias, free
            y = dot2acc(pv, wv, y);
        }
        zx[(size_t)n * 128 + 64 + lane] = __float2half(y);
    }
    // ---- count phase: per-virtual-XCD histogram (cnt8 pre-zeroed) ----
    const int myc = (blockIdx.x & 7) * NN;
    const unsigned int xcdbits = (unsigned int)(blockIdx.x & 7) << 12;
    int i = blockIdx.x * 256 + threadIdx.x;
    int stride = gridDim.x * 256;
    for (int e = i; e < NE; e += stride) {
        int r = __builtin_nontemporal_load(&ei[e]);
        int rk = atomicAdd(&cnt8[myc + r], 1);
        // [r:17][xcd:3][rank:12]
        __builtin_nontemporal_store(((unsigned int)r << 15) | xcdbits | (unsigned int)rk,
                                    &rankr[e]);
    }
}

// ---------------- K_scan: single-kernel exclusive scan (aggregate publish + spin) ----------------
// agg[0..390]: block aggregates; agg[AGG_COUNTER]: done counter. Zeroed by host memset.
// All 391 blocks (1 KB LDS, small VGPR) are trivially co-resident -> spin is safe.
__global__ __launch_bounds__(256) void k_scan(const int* __restrict__ cnt8,
                                              int* __restrict__ agg,
                                              int* __restrict__ row_start,
                                              int* __restrict__ row_start8,
                                              int* __restrict__ tot) {
    __shared__ int sh[256];
    const int tid = threadIdx.x;
    const int bid = blockIdx.x;
    int gid = bid * 256 + tid;
    int c[8];
    int s8 = 0;
    if (gid < NN) {
#pragma unroll
        for (int k = 0; k < 8; ++k) {
            c[k] = cnt8[k * NN + gid];
            s8 += c[k];
        }
    }
    // block-local inclusive scan (Kogge-Stone)
    sh[tid] = s8;
    __syncthreads();
    for (int off = 1; off < 256; off <<= 1) {
        int t = (tid >= off) ? sh[tid - off] : 0;
        __syncthreads();
        sh[tid] += t;
        __syncthreads();
    }
    int incl = sh[tid];
    // publish aggregate (agent scope, release), bump done counter
    if (tid == 255) {
        __hip_atomic_store(&agg[bid], incl, __ATOMIC_RELEASE, __HIP_MEMORY_SCOPE_AGENT);
        __hip_atomic_fetch_add(&agg[AGG_COUNTER], 1, __ATOMIC_RELEASE, __HIP_MEMORY_SCOPE_AGENT);
    }
    // wait for all aggregates
    if (tid == 0) {
        while (__hip_atomic_load(&agg[AGG_COUNTER], __ATOMIC_ACQUIRE, __HIP_MEMORY_SCOPE_AGENT) < NBLK) {
        }
    }
    __syncthreads();
    // sum predecessors' aggregates (each thread <=2 agent-scope loads, then LDS reduce)
    int mysum = 0;
    for (int j = tid; j < bid; j += 256)
        mysum += __hip_atomic_load(&agg[j], __ATOMIC_RELAXED, __HIP_MEMORY_SCOPE_AGENT);
    sh[tid] = mysum;
    __syncthreads();
    for (int off = 128; off; off >>= 1) {
        if (tid < off) sh[tid] += sh[tid + off];
        __syncthreads();
    }
    int bbase = sh[0];
    if (gid >= NN) return;
    int ex = bbase + incl - s8;  // global exclusive prefix
    row_start[gid] = ex;
    tot[gid] = s8;
    int base = ex;
#pragma unroll
    for (int k = 0; k < 8; ++k) {
        row_start8[k * NN + gid] = base;
        base += c[k];
    }
}

// ---------------- K_place: atomic-free colidx scatter, 2 edges per thread ----------------
__global__ __launch_bounds__(256) void k_place(const int* __restrict__ ei,
                                               const unsigned int* __restrict__ rankr,
                                               const int* __restrict__ row_start8,
                                               int* __restrict__ colidx) {
    int e0 = (blockIdx.x * 256 + threadIdx.x) * 2;
    if (e0 >= NE) return;
    uint2v rr = __builtin_nontemporal_load((const uint2v*)(rankr + e0));
    int2v cc = __builtin_nontemporal_load((const int2v*)(ei + NE + e0));
    int r0 = (int)(rr.x >> 15), x0 = (int)((rr.x >> 12) & 7u), k0 = (int)(rr.x & 0xFFFu);
    int r1 = (int)(rr.y >> 15), x1 = (int)((rr.y >> 12) & 7u), k1 = (int)(rr.y & 0xFFFu);
    __builtin_nontemporal_store(cc.x, &colidx[row_start8[x0 * NN + r0] + k0]);
    __builtin_nontemporal_store(cc.y, &colidx[row_start8[x1 * NN + r1] + k1]);
}

// ---------------- K_node: 4 nodes per wave (16 lanes each); fused dot+exp+softmax+gather ----------------
__global__ __launch_bounds__(256) void k_node(const __half* __restrict__ zx,
                                              const int* __restrict__ colidx,
                                              const int* __restrict__ row_start,
                                              const int* __restrict__ tot,
                                              const float* __restrict__ b,
                                              const float* __restrict__ alpha_p,
                                              const float* __restrict__ bias_p,
                                              float* __restrict__ out) {
    const int lane = threadIdx.x & 63;
    const int sub = lane & 15;  // edge slot within my node's group
    int w = (blockIdx.x * blockDim.x + threadIdx.x) >> 6;
    int nb = w * 4;  // 4 nodes per wave; grid sized exactly
    int n = nb + (lane >> 4);
    const float alpha = *alpha_p;
    const float bias = *bias_p;
    const float Mest = fabsf(alpha) + bias;  // >= max logit since |corr| <= 1
    int rs = row_start[n];
    int c = tot[n];
    float bv = b[lane];
    const float4* zi4 = (const float4*)(zx + (size_t)n * 128);
    float4 zi[8];
#pragma unroll
    for (int k = 0; k < 8; ++k) zi[k] = zi4[k];
    int cmax = c;
    cmax = max(cmax, __shfl_xor(cmax, 16));
    cmax = max(cmax, __shfl_xor(cmax, 32));
    float a0A = 0.0f, a0B = 0.0f, a1A = 0.0f, a1B = 0.0f;
    float a2A = 0.0f, a2B = 0.0f, a3A = 0.0f, a3B = 0.0f;
    float dsum = 0.0f;
    for (int base = 0; base < cmax; base += 16) {
        int idx = base + sub;
        bool valid = idx < c;
        int col = valid ? colidx[rs + idx] : 0;
        // ---- phase A: in-lane dot(zn[n], zn[col]), 4 independent fdot2 chains ----
        const float4* zj4 = (const float4*)(zx + (size_t)col * 128);
        float4 zj[8];
#pragma unroll
        for (int k = 0; k < 8; ++k) zj[k] = zj4[k];
        float d0 = 0.0f, d1 = 0.0f, d2 = 0.0f, d3 = 0.0f;
#pragma unroll
        for (int k = 0; k < 8; ++k) {
            const int* ha = (const int*)&zi[k];
            const unsigned int* hb = (const unsigned int*)&zj[k];
            d0 = dot2acc(ha[0], hb[0], d0);
            d1 = dot2acc(ha[1], hb[1], d1);
            d2 = dot2acc(ha[2], hb[2], d2);
            d3 = dot2acc(ha[3], hb[3], d3);
        }
        float dot = (d0 + d1) + (d2 + d3);
        float ex = valid ? __expf(alpha * dot + bias - Mest) : 0.0f;
        unsigned int pk = pack_entry(col, ex);
        // group-local denom butterfly (4 steps over 16 lanes)
        float t = ex;
        t += __shfl_xor(t, 1);
        t += __shfl_xor(t, 2);
        t += __shfl_xor(t, 4);
        t += __shfl_xor(t, 8);
        dsum += t;
        // ---- phase B: per group, broadcast + coalesced xw gather ----
#define PHASE_B(GG, ACCA, ACCB)                                                                    \
        {                                                                                          \
            int cg = __shfl(c, GG * 16);                                                           \
            int mg = cg - base;                                                                    \
            mg = mg > 16 ? 16 : mg;                                                               \
            int j = 0;                                                                             \
            for (; j + 4 <= mg; j += 4) {                                                          \
                unsigned int q0 = (unsigned int)__builtin_amdgcn_readlane((int)pk, GG * 16 + j);   \
                unsigned int q1 = (unsigned int)__builtin_amdgcn_readlane((int)pk, GG * 16 + j + 1); \
                unsigned int q2 = (unsigned int)__builtin_amdgcn_readlane((int)pk, GG * 16 + j + 2); \
                unsigned int q3 = (unsigned int)__builtin_amdgcn_readlane((int)pk, GG * 16 + j + 3); \
                float x0 = __half2float(zx[(size_t)(q0 >> 15) * 128 + 64 + lane]);                 \
                float x1 = __half2float(zx[(size_t)(q1 >> 15) * 128 + 64 + lane]);                 \
                float x2 = __half2float(zx[(size_t)(q2 >> 15) * 128 + 64 + lane]);                 \
                float x3 = __half2float(zx[(size_t)(q3 >> 15) * 128 + 64 + lane]);                 \
                ACCA = fmaf(unpack_ex(q0), x0, ACCA);                                              \
                ACCB = fmaf(unpack_ex(q1), x1, ACCB);                                              \
                ACCA = fmaf(unpack_ex(q2), x2, ACCA);                                              \
                ACCB = fmaf(unpack_ex(q3), x3, ACCB);                                              \
            }                                                                                      \
            for (; j < mg; ++j) {                                                                  \
                unsigned int q0 = (unsigned int)__builtin_amdgcn_readlane((int)pk, GG * 16 + j);   \
                float x0 = __half2float(zx[(size_t)(q0 >> 15) * 128 + 64 + lane]);                 \
                ACCA = fmaf(unpack_ex(q0), x0, ACCA);                                              \
            }                                                                                      \
        }
        PHASE_B(0, a0A, a0B)
        PHASE_B(1, a1A, a1B)
        PHASE_B(2, a2A, a2B)
        PHASE_B(3, a3A, a3B)
#undef PHASE_B
    }
    float dg0 = __shfl(dsum, 0);
    float dg1 = __shfl(dsum, 16);
    float dg2 = __shfl(dsum, 32);
    float dg3 = __shfl(dsum, 48);
    out[(size_t)(nb + 0) * D + lane] = (a0A + a0B) / (dg0 + 1e-9f) + bv;
    out[(size_t)(nb + 1) * D + lane] = (a1A + a1B) / (dg1 + 1e-9f) + bv;
    out[(size_t)(nb + 2) * D + lane] = (a2A + a2B) / (dg2 + 1e-9f) + bv;
    out[(size_t)(nb + 3) * D + lane] = (a3A + a3B) / (dg3 + 1e-9f) + bv;
}

extern "C" void kernel_launch(void* const* d_in, const int* in_sizes, int n_in,
                              void* d_out, int out_size, void* d_ws, size_t ws_size,
                              hipStream_t stream) {
    const float* x = (const float*)d_in[0];
    const int* ei = (const int*)d_in[1];  // [2, NE] int32
    const float* z = (const float*)d_in[2];
    const float* W = (const float*)d_in[3];
    const float* b = (const float*)d_in[4];
    const float* alpha = (const float*)d_in[5];
    const float* bias_edge = (const float*)d_in[6];
    float* out = (float*)d_out;  // [NN, D]

    // workspace layout (~46 MB)
    char* ws = (char*)d_ws;
    size_t off = 0;
    __half* zx = (__half*)(ws + off); off += (size_t)NN * 128 * 2;           // 25.6 MB
    int* colidx = (int*)(ws + off); off += (size_t)NE * 4;                   // 6.4 MB
    unsigned int* rankr = (unsigned int*)(ws + off); off += (size_t)NE * 4;  // 6.4 MB
    int* cnt8 = (int*)(ws + off); off += (size_t)8 * NN * 4;                 // 3.2 MB
    int* agg = (int*)(ws + off); off += 512 * 4;                             // aggregates + counter
    int* row_start8 = (int*)(ws + off); off += (size_t)8 * NN * 4;           // 3.2 MB
    int* row_start = (int*)(ws + off); off += (size_t)NN * 4;
    int* tot = (int*)(ws + off); off += (size_t)NN * 4;

    // zero cnt8 AND agg in one memset (they are adjacent)
    hipMemsetAsync(cnt8, 0, (size_t)8 * NN * 4 + 512 * 4, stream);
    k_prep_count<<<4096, 256, 0, stream>>>(z, x, W, zx, ei, cnt8, rankr);
    k_scan<<<NBLK, 256, 0, stream>>>(cnt8, agg, row_start, row_start8, tot);
    k_place<<<(NE / 2 + 255) / 256, 256, 0, stream>>>(ei, rankr, row_start8, colidx);
    // 4 nodes per wave, 16 nodes per 256-thread block -> exactly NN/16 = 6250 blocks
    k_node<<<NN / 16, 256, 0, stream>>>(zx, colidx, row_start, tot, b, alpha, bias_edge, out);
}

// Round 19
// 229.415 us; speedup vs baseline: 1.1677x; 1.1120x over previous
//
#include <hip/hip_runtime.h>
#include <hip/hip_fp16.h>
#include <math.h>

#define NN 100000
#define NE 1600000
#define D  64
#define NBLK 391  // ceil(NN/256)

typedef _Float16 half2v __attribute__((ext_vector_type(2)));

// in-register packed entry: [col:17][ex_fp16_no_sign:15]  (col < 2^17, ex in (0,1])
__device__ __forceinline__ unsigned int pack_entry(int col, float ex) {
    unsigned short hb = __half_as_ushort(__float2half(ex));
    return ((unsigned int)col << 15) | (unsigned int)(hb & 0x7FFFu);
}
__device__ __forceinline__ float unpack_ex(unsigned int pk) {
    return __half2float(__ushort_as_half((unsigned short)(pk & 0x7FFFu)));
}

__device__ __forceinline__ float dot2acc(int a, unsigned int b, float c) {
#if defined(__has_builtin) && __has_builtin(__builtin_amdgcn_fdot2)
    return __builtin_amdgcn_fdot2(__builtin_bit_cast(half2v, a),
                                  __builtin_bit_cast(half2v, b), c, false);
#else
    float2 fa = __half22float2(*(const __half2*)&a);
    float2 fb = __half22float2(*(const __half2*)&b);
    return fmaf(fa.y, fb.y, fmaf(fa.x, fb.x, c));
#endif
}

// ---------------- K_prep_count: zx[n][0:64]=z/||z||, zx[n][64:128]=x@W^T (fp16);
//                  count phase into per-virtual-XCD histogram cnt8[bid&7][r] ----------------
__global__ __launch_bounds__(256) void k_prep_count(const float* __restrict__ z,
                                                    const float* __restrict__ x,
                                                    const float* __restrict__ W,
                                                    __half* __restrict__ zx,
                                                    const int* __restrict__ ei,
                                                    int* __restrict__ cnt8,
                                                    unsigned int* __restrict__ rankr) {
    __shared__ unsigned int WtP[32 * 64];  // WtP[d2*64 + j] = half2(W[j][2*d2], W[j][2*d2+1]), 8 KB
    {
        const float2* W2 = (const float2*)W;
        for (int i = threadIdx.x; i < 2048; i += 256) {
            int j = i >> 5, d2 = i & 31;
            float2 wp = W2[j * 32 + d2];  // coalesced pair read of row j
            half2v h;
            h.x = (_Float16)wp.x;
            h.y = (_Float16)wp.y;
            WtP[d2 * 64 + j] = __builtin_bit_cast(unsigned int, h);
        }
    }
    __syncthreads();
    const int lane = threadIdx.x & 63;
    int wave = blockIdx.x * 4 + (threadIdx.x >> 6);
    int nWaves = gridDim.x * 4;
    for (int n = wave; n < NN; n += nWaves) {
        float zv = z[n * D + lane];
        float s = zv * zv;
#pragma unroll
        for (int off = 32; off; off >>= 1) s += __shfl_xor(s, off);
        float inv = 1.0f / sqrtf(fmaxf(s, 1e-18f));
        zx[(size_t)n * 128 + lane] = __float2half(zv * inv);
        // pack x row into lane-held half2 pairs: lane i holds (x[2*(i&31)], x[2*(i&31)+1])
        float xv = x[n * D + lane];
        float pa = __shfl(xv, 2 * (lane & 31));
        float pb = __shfl(xv, 2 * (lane & 31) + 1);
        half2v pkh;
        pkh.x = (_Float16)pa;
        pkh.y = (_Float16)pb;
        int pki = __builtin_bit_cast(int, pkh);
        float y = 0.0f;
#pragma unroll
        for (int d2 = 0; d2 < 32; ++d2) {
            int pv = __shfl(pki, d2);               // (x[2*d2], x[2*d2+1]) broadcast
            unsigned int wv = WtP[d2 * 64 + lane];  // conflict-free (2-way alias, free)
            y = dot2acc(pv, wv, y);
        }
        zx[(size_t)n * 128 + 64 + lane] = __float2half(y);
    }
    // ---- count phase: per-virtual-XCD histogram (cnt8 pre-zeroed) ----
    const int myc = (blockIdx.x & 7) * NN;
    const unsigned int xcdbits = (unsigned int)(blockIdx.x & 7) << 12;
    int i = blockIdx.x * 256 + threadIdx.x;
    int stride = gridDim.x * 256;
    for (int e = i; e < NE; e += stride) {
        int r = __builtin_nontemporal_load(&ei[e]);
        int rk = atomicAdd(&cnt8[myc + r], 1);
        // [r:17][xcd:3][rank:12]
        __builtin_nontemporal_store(((unsigned int)r << 15) | xcdbits | (unsigned int)rk,
                                    &rankr[e]);
    }
}

// ---------------- scan: exclusive prefix sum over row totals ----------------
__global__ __launch_bounds__(256) void k_scan1(const int* __restrict__ cnt8,
                                               int* __restrict__ inc,
                                               int* __restrict__ bsum) {
    __shared__ int sh[256];
    int gid = blockIdx.x * 256 + threadIdx.x;
    int v = 0;
    if (gid < NN) {
#pragma unroll
        for (int k = 0; k < 8; ++k) v += cnt8[k * NN + gid];
    }
    sh[threadIdx.x] = v;
    __syncthreads();
    for (int off = 1; off < 256; off <<= 1) {
        int t = (threadIdx.x >= off) ? sh[threadIdx.x - off] : 0;
        __syncthreads();
        sh[threadIdx.x] += t;
        __syncthreads();
    }
    if (gid < NN) inc[gid] = sh[threadIdx.x];
    if (threadIdx.x == 255) bsum[blockIdx.x] = sh[255];
}

__global__ __launch_bounds__(512) void k_scan2(int* __restrict__ bsum) {
    __shared__ int sh[512];
    int v = (threadIdx.x < NBLK) ? bsum[threadIdx.x] : 0;
    sh[threadIdx.x] = v;
    __syncthreads();
    for (int off = 1; off < 512; off <<= 1) {
        int t = (threadIdx.x >= off) ? sh[threadIdx.x - off] : 0;
        __syncthreads();
        sh[threadIdx.x] += t;
        __syncthreads();
    }
    if (threadIdx.x < NBLK) bsum[threadIdx.x] = sh[threadIdx.x] - v;  // exclusive
}

__global__ __launch_bounds__(256) void k_scan3(const int* __restrict__ cnt8,
                                               const int* __restrict__ inc,
                                               const int* __restrict__ bsum,
                                               int* __restrict__ row_start,
                                               int* __restrict__ row_start8,
                                               int* __restrict__ tot) {
    int gid = blockIdx.x * 256 + threadIdx.x;
    if (gid >= NN) return;
    int c[8];
    int s8 = 0;
#pragma unroll
    for (int k = 0; k < 8; ++k) {
        c[k] = cnt8[k * NN + gid];
        s8 += c[k];
    }
    int ex = inc[gid] - s8 + bsum[blockIdx.x];
    row_start[gid] = ex;
    tot[gid] = s8;
    int base = ex;
#pragma unroll
    for (int k = 0; k < 8; ++k) {
        row_start8[k * NN + gid] = base;
        base += c[k];
    }
}

// ---------------- K_place: atomic-free colidx scatter via per-XCD offsets ----------------
__global__ __launch_bounds__(256) void k_place(const int* __restrict__ ei,
                                               const unsigned int* __restrict__ rankr,
                                               const int* __restrict__ row_start8,
                                               int* __restrict__ colidx) {
    int e = blockIdx.x * 256 + threadIdx.x;
    if (e >= NE) return;
    unsigned int rr = __builtin_nontemporal_load(&rankr[e]);
    int c = __builtin_nontemporal_load(&ei[NE + e]);
    int r = (int)(rr >> 15);
    int xcd = (int)((rr >> 12) & 7u);
    int rk = (int)(rr & 0xFFFu);
    __builtin_nontemporal_store(c, &colidx[row_start8[xcd * NN + r] + rk]);
}

// ---------------- K_node: 4 nodes per wave (16 lanes each); fused dot+exp+softmax+gather ----------------
__global__ __launch_bounds__(256) void k_node(const __half* __restrict__ zx,
                                              const int* __restrict__ colidx,
                                              const int* __restrict__ row_start,
                                              const int* __restrict__ tot,
                                              const float* __restrict__ b,
                                              const float* __restrict__ alpha_p,
                                              const float* __restrict__ bias_p,
                                              float* __restrict__ out) {
    const int lane = threadIdx.x & 63;
    const int sub = lane & 15;  // edge slot within my node's group
    int w = (blockIdx.x * blockDim.x + threadIdx.x) >> 6;
    int nb = w * 4;  // 4 nodes per wave; grid sized exactly
    int n = nb + (lane >> 4);
    const float alpha = *alpha_p;
    const float bias = *bias_p;
    const float Mest = fabsf(alpha) + bias;  // >= max logit since |corr| <= 1
    int rs = row_start[n];
    int c = tot[n];
    float bv = b[lane];
    const float4* zi4 = (const float4*)(zx + (size_t)n * 128);
    float4 zi[8];
#pragma unroll
    for (int k = 0; k < 8; ++k) zi[k] = zi4[k];
    int cmax = c;
    cmax = max(cmax, __shfl_xor(cmax, 16));
    cmax = max(cmax, __shfl_xor(cmax, 32));
    float a0A = 0.0f, a0B = 0.0f, a1A = 0.0f, a1B = 0.0f;
    float a2A = 0.0f, a2B = 0.0f, a3A = 0.0f, a3B = 0.0f;
    float dsum = 0.0f;
    for (int base = 0; base < cmax; base += 16) {
        int idx = base + sub;
        bool valid = idx < c;
        int col = valid ? colidx[rs + idx] : 0;
        // ---- phase A: in-lane dot(zn[n], zn[col]), 4 independent fdot2 chains ----
        const float4* zj4 = (const float4*)(zx + (size_t)col * 128);
        float4 zj[8];
#pragma unroll
        for (int k = 0; k < 8; ++k) zj[k] = zj4[k];
        float d0 = 0.0f, d1 = 0.0f, d2 = 0.0f, d3 = 0.0f;
#pragma unroll
        for (int k = 0; k < 8; ++k) {
            const int* ha = (const int*)&zi[k];
            const unsigned int* hb = (const unsigned int*)&zj[k];
            d0 = dot2acc(ha[0], hb[0], d0);
            d1 = dot2acc(ha[1], hb[1], d1);
            d2 = dot2acc(ha[2], hb[2], d2);
            d3 = dot2acc(ha[3], hb[3], d3);
        }
        float dot = (d0 + d1) + (d2 + d3);
        float ex = valid ? __expf(alpha * dot + bias - Mest) : 0.0f;
        unsigned int pk = pack_entry(col, ex);
        // group-local denom butterfly (4 steps over 16 lanes)
        float t = ex;
        t += __shfl_xor(t, 1);
        t += __shfl_xor(t, 2);
        t += __shfl_xor(t, 4);
        t += __shfl_xor(t, 8);
        dsum += t;
        // ---- phase B: per group, broadcast + coalesced xw gather ----
#define PHASE_B(GG, ACCA, ACCB)                                                                    \
        {                                                                                          \
            int cg = __shfl(c, GG * 16);                                                           \
            int mg = cg - base;                                                                    \
            mg = mg > 16 ? 16 : mg;                                                               \
            int j = 0;                                                                             \
            for (; j + 4 <= mg; j += 4) {                                                          \
                unsigned int q0 = (unsigned int)__builtin_amdgcn_readlane((int)pk, GG * 16 + j);   \
                unsigned int q1 = (unsigned int)__builtin_amdgcn_readlane((int)pk, GG * 16 + j + 1); \
                unsigned int q2 = (unsigned int)__builtin_amdgcn_readlane((int)pk, GG * 16 + j + 2); \
                unsigned int q3 = (unsigned int)__builtin_amdgcn_readlane((int)pk, GG * 16 + j + 3); \
                float x0 = __half2float(zx[(size_t)(q0 >> 15) * 128 + 64 + lane]);                 \
                float x1 = __half2float(zx[(size_t)(q1 >> 15) * 128 + 64 + lane]);                 \
                float x2 = __half2float(zx[(size_t)(q2 >> 15) * 128 + 64 + lane]);                 \
                float x3 = __half2float(zx[(size_t)(q3 >> 15) * 128 + 64 + lane]);                 \
                ACCA = fmaf(unpack_ex(q0), x0, ACCA);                                              \
                ACCB = fmaf(unpack_ex(q1), x1, ACCB);                                              \
                ACCA = fmaf(unpack_ex(q2), x2, ACCA);                                              \
                ACCB = fmaf(unpack_ex(q3), x3, ACCB);                                              \
            }                                                                                      \
            for (; j < mg; ++j) {                                                                  \
                unsigned int q0 = (unsigned int)__builtin_amdgcn_readlane((int)pk, GG * 16 + j);   \
                float x0 = __half2float(zx[(size_t)(q0 >> 15) * 128 + 64 + lane]);                 \
                ACCA = fmaf(unpack_ex(q0), x0, ACCA);                                              \
            }                                                                                      \
        }
        PHASE_B(0, a0A, a0B)
        PHASE_B(1, a1A, a1B)
        PHASE_B(2, a2A, a2B)
        PHASE_B(3, a3A, a3B)
#undef PHASE_B
    }
    float dg0 = __shfl(dsum, 0);
    float dg1 = __shfl(dsum, 16);
    float dg2 = __shfl(dsum, 32);
    float dg3 = __shfl(dsum, 48);
    out[(size_t)(nb + 0) * D + lane] = (a0A + a0B) / (dg0 + 1e-9f) + bv;
    out[(size_t)(nb + 1) * D + lane] = (a1A + a1B) / (dg1 + 1e-9f) + bv;
    out[(size_t)(nb + 2) * D + lane] = (a2A + a2B) / (dg2 + 1e-9f) + bv;
    out[(size_t)(nb + 3) * D + lane] = (a3A + a3B) / (dg3 + 1e-9f) + bv;
}

extern "C" void kernel_launch(void* const* d_in, const int* in_sizes, int n_in,
                              void* d_out, int out_size, void* d_ws, size_t ws_size,
                              hipStream_t stream) {
    const float* x = (const float*)d_in[0];
    const int* ei = (const int*)d_in[1];  // [2, NE] int32
    const float* z = (const float*)d_in[2];
    const float* W = (const float*)d_in[3];
    const float* b = (const float*)d_in[4];
    const float* alpha = (const float*)d_in[5];
    const float* bias_edge = (const float*)d_in[6];
    float* out = (float*)d_out;  // [NN, D]

    // workspace layout (~46 MB)
    char* ws = (char*)d_ws;
    size_t off = 0;
    __half* zx = (__half*)(ws + off); off += (size_t)NN * 128 * 2;           // 25.6 MB
    int* colidx = (int*)(ws + off); off += (size_t)NE * 4;                   // 6.4 MB
    unsigned int* rankr = (unsigned int*)(ws + off); off += (size_t)NE * 4;  // 6.4 MB
    int* cnt8 = (int*)(ws + off); off += (size_t)8 * NN * 4;                 // 3.2 MB
    int* row_start8 = (int*)(ws + off); off += (size_t)8 * NN * 4;           // 3.2 MB
    int* inc = (int*)(ws + off); off += (size_t)NN * 4;
    int* row_start = (int*)(ws + off); off += (size_t)NN * 4;
    int* tot = (int*)(ws + off); off += (size_t)NN * 4;
    int* bsum = (int*)(ws + off); off += 512 * 4;

    hipMemsetAsync(cnt8, 0, (size_t)8 * NN * 4, stream);
    k_prep_count<<<4096, 256, 0, stream>>>(z, x, W, zx, ei, cnt8, rankr);
    k_scan1<<<NBLK, 256, 0, stream>>>(cnt8, inc, bsum);
    k_scan2<<<1, 512, 0, stream>>>(bsum);
    k_scan3<<<NBLK, 256, 0, stream>>>(cnt8, inc, bsum, row_start, row_start8, tot);
    k_place<<<(NE + 255) / 256, 256, 0, stream>>>(ei, rankr, row_start8, colidx);
    // 4 nodes per wave, 16 nodes per 256-thread block -> exactly NN/16 = 6250 blocks
    k_node<<<NN / 16, 256, 0, stream>>>(zx, colidx, row_start, tot, b, alpha, bias_edge, out);
}